// Round 3
// baseline (512.274 us; speedup 1.0000x reference)
//
#include <hip/hip_runtime.h>

// msg[b,o,n] = sum_d We[o,d]*e_vw[b,d,n] + sum_d Ww[o,d]*h_w[b,d,n] + be[o]+bw[o]
// B=128, D=768, N=256. Fused GEMM: M=768, N=256, K=1536 per batch.
// Pre-kernel: Wcat = [We|Ww] as bf16 [768][1536] in d_ws.
// Main: 128x128 tile, BK=32, 4 waves, mfma_f32_16x16x32_bf16.
// 2-deep register prefetch for BOTH A and B, dbuf LDS, 4 blocks/CU.

#define DD   768
#define NCOL 256
#define KTOT 1536
#define BM   128
#define BN   128
#define BK   32
#define NIT  48

typedef __bf16 bf16;
typedef __attribute__((ext_vector_type(8))) __bf16 bf16x8;
typedef __attribute__((ext_vector_type(4))) float f32x4;
typedef __attribute__((ext_vector_type(2))) float f32x2;
typedef __attribute__((ext_vector_type(4))) unsigned int u32x4;

// XOR swizzle on bits 4-6 using row bits 1-3: 0 measured bank conflicts.
__device__ __forceinline__ int swz(int row, int kbyte) {
  return (row * 64 + kbyte) ^ (((row >> 1) & 7) << 4);
}

// ---- pre-kernel: Wcat[o][k] bf16 ; k<768 -> We, else Ww ----
__global__ void prep_w(const float* __restrict__ We, const float* __restrict__ Ww,
                       unsigned short* __restrict__ Wcat) {
  int i = blockIdx.x * blockDim.x + threadIdx.x;
  int base = i * 8;
  int o = base / KTOT;
  int k = base % KTOT;
  const float* src = (k < DD) ? (We + (size_t)o * DD + k)
                              : (Ww + (size_t)o * DD + (k - DD));
  f32x4 v0 = *(const f32x4*)src;
  f32x4 v1 = *(const f32x4*)(src + 4);
  union { bf16 h[8]; u32x4 q; } u;
  u.h[0]=(bf16)v0[0]; u.h[1]=(bf16)v0[1]; u.h[2]=(bf16)v0[2]; u.h[3]=(bf16)v0[3];
  u.h[4]=(bf16)v1[0]; u.h[5]=(bf16)v1[1]; u.h[6]=(bf16)v1[2]; u.h[7]=(bf16)v1[3];
  *(u32x4*)(Wcat + (size_t)o * KTOT + k) = u.q;
}

__global__ __launch_bounds__(256, 4)
void msg_kernel(const float* __restrict__ h_w, const float* __restrict__ e_vw,
                const unsigned short* __restrict__ Wcat,
                const float* __restrict__ be, const float* __restrict__ bw,
                float* __restrict__ out) {
  // buf0: A @0, B @8192 ; buf1: A @16384, B @24576
  __shared__ __align__(16) unsigned char smem[2 * 16384];
  __shared__ float bias_s[BM];

  const int tid = threadIdx.x;
  // XCD-chunked bijective swizzle; 6 row-blocks sharing a B panel are
  // consecutive logical ids -> same XCD L2.
  const int b  = blockIdx.x;
  const int lb = (b & 7) * 192 + (b >> 3);
  const int y  = lb % 6;
  const int g  = lb / 6;
  const int bm0 = y * BM;
  const int bn0 = (g & 1) * BN;
  const int bb  = g >> 1;

  if (tid < BM) bias_s[tid] = be[bm0 + tid] + bw[bm0 + tid];

  // ---- A staging map: row = tid>>1, k-half = tid&1 (16 bf16 = 32B) ----
  const int rowA = tid >> 1, kh = tid & 1;
  const unsigned short* pA0 = Wcat + (size_t)(bm0 + rowA) * KTOT + kh * 16;
  const int wA0 = swz(rowA, kh * 32);
  const int wA1 = swz(rowA, kh * 32 + 16);

  // ---- B staging map: 8k x 2n micro-block; nb = tid&63, kb = wave id ----
  const int nb = tid & 63, kbw = tid >> 6;
  const size_t bofs = (size_t)bb * DD * NCOL + (size_t)(kbw * 8) * NCOL + bn0 + nb * 2;
  const float* pE = e_vw + bofs;
  const float* pH = h_w  + bofs;
  const int wB0 = swz(2 * nb,     kbw * 16);
  const int wB1 = swz(2 * nb + 1, kbw * 16);

  u32x4 aE0, aE1, aO0, aO1;  // A prefetch regs, even/odd tiles (bf16 bits)
  float bEr[16], bOr[16];    // B prefetch regs, even/odd tiles

  auto issueA = [&](int T, u32x4& r0, u32x4& r1) {
    const unsigned short* p = pA0 + T * BK;
    r0 = *(const u32x4*)p;
    r1 = *(const u32x4*)(p + 8);
  };
  auto storeA = [&](int buf, const u32x4& r0, const u32x4& r1) {
    unsigned char* base = smem + buf * 16384;
    *(u32x4*)(base + wA0) = r0;
    *(u32x4*)(base + wA1) = r1;
  };
  auto issueB = [&](int T, float (&r)[16]) {
    const float* p = (T < 24) ? (pE + (size_t)T * BK * NCOL)
                              : (pH + (size_t)(T - 24) * BK * NCOL);
    #pragma unroll
    for (int kk = 0; kk < 8; ++kk) {
      f32x2 v = *(const f32x2*)(p + (size_t)kk * NCOL);
      r[2 * kk] = v[0]; r[2 * kk + 1] = v[1];
    }
  };
  auto storeB = [&](int buf, const float (&r)[16]) {
    unsigned char* base = smem + buf * 16384 + 8192;
    union { bf16 h[8]; u32x4 q; } r0, r1;
    #pragma unroll
    for (int kk = 0; kk < 8; ++kk) {
      r0.h[kk] = (bf16)r[2 * kk];
      r1.h[kk] = (bf16)r[2 * kk + 1];
    }
    *(u32x4*)(base + wB0) = r0.q;
    *(u32x4*)(base + wB1) = r1.q;
  };

  // ---- compute map: 4 waves 2x2, wave tile 64x64 ----
  const int lane = tid & 63, wid = tid >> 6;
  const int wm = wid >> 1, wn = wid & 1;
  const int lr = lane & 15, kch = (lane >> 4) * 16;
  f32x4 acc[4][4] = {};

  auto compute = [&](int buf) {
    const unsigned char* base = smem + buf * 16384;
    bf16x8 af[4], bfr[4];
    #pragma unroll
    for (int m = 0; m < 4; ++m)
      af[m] = *(const bf16x8*)(base + swz(wm * 64 + m * 16 + lr, kch));
    #pragma unroll
    for (int n = 0; n < 4; ++n)
      bfr[n] = *(const bf16x8*)(base + 8192 + swz(wn * 64 + n * 16 + lr, kch));
    #pragma unroll
    for (int m = 0; m < 4; ++m)
      #pragma unroll
      for (int n = 0; n < 4; ++n)
        acc[m][n] = __builtin_amdgcn_mfma_f32_16x16x32_bf16(af[m], bfr[n], acc[m][n], 0, 0, 0);
  };

  // ---- prologue: tiles 0,1 ----
  issueB(0, bEr);
  issueA(0, aE0, aE1);
  storeA(0, aE0, aE1);
  storeB(0, bEr);
  issueB(1, bOr);
  issueA(1, aO0, aO1);
  __syncthreads();

  // ---- main loop: tiles 0..45 computed here; issue depth 2 for A and B ----
  for (int it = 0; it < 46; it += 2) {
    // even sub-step: compute tile it (buf0); store tile it+1; issue tile it+2
    issueB(it + 2, bEr);
    issueA(it + 2, aE0, aE1);
    compute(0);
    storeA(1, aO0, aO1);
    storeB(1, bOr);
    __syncthreads();

    // odd sub-step: compute tile it+1 (buf1); store tile it+2; issue tile it+3
    issueB(it + 3, bOr);
    issueA(it + 3, aO0, aO1);
    compute(1);
    storeA(0, aE0, aE1);
    storeB(0, bEr);
    __syncthreads();
  }
  // loop exits with tile 46 stored (buf0), tile 47 in aO/bOr regs
  compute(0);
  storeA(1, aO0, aO1);
  storeB(1, bOr);
  __syncthreads();
  compute(1);

  // ---- epilogue: bias + store. C/D: col=lane&15, row=(lane>>4)*4+reg ----
  float* po = out + (size_t)bb * DD * NCOL;
  const int g4 = (lane >> 4) * 4;
  #pragma unroll
  for (int m = 0; m < 4; ++m) {
    const int r0 = wm * 64 + m * 16 + g4;
    #pragma unroll
    for (int n = 0; n < 4; ++n) {
      const int col = bn0 + wn * 64 + n * 16 + lr;
      #pragma unroll
      for (int j = 0; j < 4; ++j)
        po[(size_t)(bm0 + r0 + j) * NCOL + col] = acc[m][n][j] + bias_s[r0 + j];
    }
  }
}

extern "C" void kernel_launch(void* const* d_in, const int* in_sizes, int n_in,
                              void* d_out, int out_size, void* d_ws, size_t ws_size,
                              hipStream_t stream) {
  // inputs: 0:h_v(unused) 1:h_w 2:e_vw 3:We 4:be 5:Ww 6:bw
  const float* h_w  = (const float*)d_in[1];
  const float* e_vw = (const float*)d_in[2];
  const float* We   = (const float*)d_in[3];
  const float* be   = (const float*)d_in[4];
  const float* Ww   = (const float*)d_in[5];
  const float* bw   = (const float*)d_in[6];
  float* out = (float*)d_out;
  unsigned short* Wcat = (unsigned short*)d_ws;  // 768*1536*2 = 2.36 MB

  prep_w<<<dim3(KTOT * DD / 8 / 256), 256, 0, stream>>>(We, Ww, Wcat);
  msg_kernel<<<dim3(1536), 256, 0, stream>>>(h_w, e_vw, Wcat, be, bw, out);
}

// Round 4
// 177.225 us; speedup vs baseline: 2.8905x; 2.8905x over previous
//
#include <hip/hip_runtime.h>

// msg[b,o,n] = sum_d We[o,d]*e_vw[b,d,n] + sum_d Ww[o,d]*h_w[b,d,n] + be[o]+bw[o]
// B=128, D=768, N=256. Fused GEMM: M=768, N=256, K=1536 per batch.
// Pre-kernel: Wcat = [We|Ww] as bf16 [768][1536] in d_ws.
// Main: 128x128 tile, BK=32, 4 waves, mfma_f32_16x16x32_bf16.
// 2-deep register prefetch (A and B), dbuf LDS, RAW barriers with
// lgkmcnt-only drain (T4): global prefetch loads stay in flight across
// barriers; compiler inserts counted vmcnt at consumption.

#define DD   768
#define NCOL 256
#define KTOT 1536
#define BM   128
#define BN   128
#define BK   32
#define NIT  48

typedef __bf16 bf16;
typedef __attribute__((ext_vector_type(8))) __bf16 bf16x8;
typedef __attribute__((ext_vector_type(4))) float f32x4;
typedef __attribute__((ext_vector_type(2))) float f32x2;
typedef __attribute__((ext_vector_type(4))) unsigned int u32x4;

// Raw barrier: LDS visibility only (lgkmcnt(0) retires my ds_writes/ds_reads).
// NO vmcnt drain -> prefetch survives the barrier.
#define BAR() do { \
    asm volatile("s_waitcnt lgkmcnt(0)" ::: "memory"); \
    __builtin_amdgcn_s_barrier(); \
  } while (0)

// XOR swizzle on bits 4-6 using row bits 1-3: 0 measured bank conflicts.
__device__ __forceinline__ int swz(int row, int kbyte) {
  return (row * 64 + kbyte) ^ (((row >> 1) & 7) << 4);
}

// ---- pre-kernel: Wcat[o][k] bf16 ; k<768 -> We, else Ww ----
__global__ void prep_w(const float* __restrict__ We, const float* __restrict__ Ww,
                       unsigned short* __restrict__ Wcat) {
  int i = blockIdx.x * blockDim.x + threadIdx.x;
  int base = i * 8;
  int o = base / KTOT;
  int k = base % KTOT;
  const float* src = (k < DD) ? (We + (size_t)o * DD + k)
                              : (Ww + (size_t)o * DD + (k - DD));
  f32x4 v0 = *(const f32x4*)src;
  f32x4 v1 = *(const f32x4*)(src + 4);
  union { bf16 h[8]; u32x4 q; } u;
  u.h[0]=(bf16)v0[0]; u.h[1]=(bf16)v0[1]; u.h[2]=(bf16)v0[2]; u.h[3]=(bf16)v0[3];
  u.h[4]=(bf16)v1[0]; u.h[5]=(bf16)v1[1]; u.h[6]=(bf16)v1[2]; u.h[7]=(bf16)v1[3];
  *(u32x4*)(Wcat + (size_t)o * KTOT + k) = u.q;
}

__global__ __launch_bounds__(256, 3)
void msg_kernel(const float* __restrict__ h_w, const float* __restrict__ e_vw,
                const unsigned short* __restrict__ Wcat,
                const float* __restrict__ be, const float* __restrict__ bw,
                float* __restrict__ out) {
  // buf0: A @0, B @8192 ; buf1: A @16384, B @24576
  __shared__ __align__(16) unsigned char smem[2 * 16384];
  __shared__ float bias_s[BM];

  const int tid = threadIdx.x;
  // XCD-chunked bijective swizzle; 6 row-blocks sharing a B panel are
  // consecutive logical ids -> same XCD L2.
  const int b  = blockIdx.x;
  const int lb = (b & 7) * 192 + (b >> 3);
  const int y  = lb % 6;
  const int g  = lb / 6;
  const int bm0 = y * BM;
  const int bn0 = (g & 1) * BN;
  const int bb  = g >> 1;

  if (tid < BM) bias_s[tid] = be[bm0 + tid] + bw[bm0 + tid];

  // ---- A staging map: row = tid>>1, k-half = tid&1 (16 bf16 = 32B) ----
  const int rowA = tid >> 1, kh = tid & 1;
  const unsigned short* pA0 = Wcat + (size_t)(bm0 + rowA) * KTOT + kh * 16;
  const int wA0 = swz(rowA, kh * 32);
  const int wA1 = swz(rowA, kh * 32 + 16);

  // ---- B staging map: 8k x 2n micro-block; nb = tid&63, kb = wave id ----
  const int nb = tid & 63, kbw = tid >> 6;
  const size_t bofs = (size_t)bb * DD * NCOL + (size_t)(kbw * 8) * NCOL + bn0 + nb * 2;
  const float* pE = e_vw + bofs;
  const float* pH = h_w  + bofs;
  const int wB0 = swz(2 * nb,     kbw * 16);
  const int wB1 = swz(2 * nb + 1, kbw * 16);

  u32x4 aE0, aE1, aO0, aO1;  // A prefetch regs, even/odd tiles (bf16 bits)
  float bEr[16], bOr[16];    // B prefetch regs, even/odd tiles

  auto issueA = [&](int T, u32x4& r0, u32x4& r1) {
    const unsigned short* p = pA0 + T * BK;
    r0 = *(const u32x4*)p;
    r1 = *(const u32x4*)(p + 8);
  };
  auto storeA = [&](int buf, const u32x4& r0, const u32x4& r1) {
    unsigned char* base = smem + buf * 16384;
    *(u32x4*)(base + wA0) = r0;
    *(u32x4*)(base + wA1) = r1;
  };
  auto issueB = [&](int T, float (&r)[16]) {
    const float* p = (T < 24) ? (pE + (size_t)T * BK * NCOL)
                              : (pH + (size_t)(T - 24) * BK * NCOL);
    #pragma unroll
    for (int kk = 0; kk < 8; ++kk) {
      f32x2 v = *(const f32x2*)(p + (size_t)kk * NCOL);
      r[2 * kk] = v[0]; r[2 * kk + 1] = v[1];
    }
  };
  auto storeB = [&](int buf, const float (&r)[16]) {
    unsigned char* base = smem + buf * 16384 + 8192;
    union { bf16 h[8]; u32x4 q; } r0, r1;
    #pragma unroll
    for (int kk = 0; kk < 8; ++kk) {
      r0.h[kk] = (bf16)r[2 * kk];
      r1.h[kk] = (bf16)r[2 * kk + 1];
    }
    *(u32x4*)(base + wB0) = r0.q;
    *(u32x4*)(base + wB1) = r1.q;
  };

  // ---- compute map: 4 waves 2x2, wave tile 64x64 ----
  const int lane = tid & 63, wid = tid >> 6;
  const int wm = wid >> 1, wn = wid & 1;
  const int lr = lane & 15, kch = (lane >> 4) * 16;
  f32x4 acc[4][4] = {};

  auto compute = [&](int buf) {
    const unsigned char* base = smem + buf * 16384;
    bf16x8 af[4], bfr[4];
    #pragma unroll
    for (int m = 0; m < 4; ++m)
      af[m] = *(const bf16x8*)(base + swz(wm * 64 + m * 16 + lr, kch));
    #pragma unroll
    for (int n = 0; n < 4; ++n)
      bfr[n] = *(const bf16x8*)(base + 8192 + swz(wn * 64 + n * 16 + lr, kch));
    #pragma unroll
    for (int m = 0; m < 4; ++m)
      #pragma unroll
      for (int n = 0; n < 4; ++n)
        acc[m][n] = __builtin_amdgcn_mfma_f32_16x16x32_bf16(af[m], bfr[n], acc[m][n], 0, 0, 0);
  };

  // ---- prologue: stage tile 0, issue tile 1 ----
  issueB(0, bEr);
  issueA(0, aE0, aE1);
  storeA(0, aE0, aE1);
  storeB(0, bEr);
  issueB(1, bOr);
  issueA(1, aO0, aO1);
  BAR();

  // ---- main loop: computes tiles 0..45; issue depth ~1.5 sub-steps ----
  for (int it = 0; it < 46; it += 2) {
    // even: compute tile it (buf0); store tile it+1 -> buf1; issue tile it+2
    issueB(it + 2, bEr);
    issueA(it + 2, aE0, aE1);
    compute(0);
    storeA(1, aO0, aO1);
    storeB(1, bOr);
    BAR();

    // odd: compute tile it+1 (buf1); store tile it+2 -> buf0; issue tile it+3
    issueB(it + 3, bOr);
    issueA(it + 3, aO0, aO1);
    compute(1);
    storeA(0, aE0, aE1);
    storeB(0, bEr);
    BAR();
  }
  // loop exits with tile 46 in buf0, tile 47 in aO/bOr regs
  compute(0);
  storeA(1, aO0, aO1);
  storeB(1, bOr);
  BAR();
  compute(1);

  // ---- epilogue: bias + store. C/D: col=lane&15, row=(lane>>4)*4+reg ----
  float* po = out + (size_t)bb * DD * NCOL;
  const int g4 = (lane >> 4) * 4;
  #pragma unroll
  for (int m = 0; m < 4; ++m) {
    const int r0 = wm * 64 + m * 16 + g4;
    #pragma unroll
    for (int n = 0; n < 4; ++n) {
      const int col = bn0 + wn * 64 + n * 16 + lr;
      #pragma unroll
      for (int j = 0; j < 4; ++j)
        po[(size_t)(bm0 + r0 + j) * NCOL + col] = acc[m][n][j] + bias_s[r0 + j];
    }
  }
}

extern "C" void kernel_launch(void* const* d_in, const int* in_sizes, int n_in,
                              void* d_out, int out_size, void* d_ws, size_t ws_size,
                              hipStream_t stream) {
  // inputs: 0:h_v(unused) 1:h_w 2:e_vw 3:We 4:be 5:Ww 6:bw
  const float* h_w  = (const float*)d_in[1];
  const float* e_vw = (const float*)d_in[2];
  const float* We   = (const float*)d_in[3];
  const float* be   = (const float*)d_in[4];
  const float* Ww   = (const float*)d_in[5];
  const float* bw   = (const float*)d_in[6];
  float* out = (float*)d_out;
  unsigned short* Wcat = (unsigned short*)d_ws;  // 768*1536*2 = 2.36 MB

  prep_w<<<dim3(KTOT * DD / 8 / 256), 256, 0, stream>>>(We, Ww, Wcat);
  msg_kernel<<<dim3(1536), 256, 0, stream>>>(h_w, e_vw, Wcat, be, bw, out);
}

// Round 5
// 123.334 us; speedup vs baseline: 4.1535x; 1.4369x over previous
//
#include <hip/hip_runtime.h>

// msg[b,o,n] = sum_d We[o,d]*e_vw[b,d,n] + sum_d Ww[o,d]*h_w[b,d,n] + be[o]+bw[o]
// B=128, D=768, N=256. Fused GEMM: M=768, N=256, K=1536 per batch.
// Block tile: FULL-M 768 x 64n (x reads HBM exactly ONCE), K-loop 48 x BK=32.
// 1024 threads = 16 waves (8m x 2n), wave tile 96x64, acc 6x2 f32x4 = 48 AGPR.
// A: Wtile bf16 pre-packed per K-tile (prep kernel) -> 3x16B loads + swizzled
//    ds_write_b128. B: 2 scalar f32 loads + cvt_pk + ds_write_b32, depth-2 regs.
// lgkm-only barriers (round-4 proven): global prefetch survives the barrier.

#define DD    768
#define NCOL  256
#define KTOT  1536
#define BM    768
#define BN    64
#define BK    32
#define NIT   48

typedef __bf16 bf16;
typedef __attribute__((ext_vector_type(8))) __bf16 bf16x8;
typedef __attribute__((ext_vector_type(4))) float f32x4;
typedef __attribute__((ext_vector_type(4))) unsigned int u32x4;

#define BAR() do { \
    asm volatile("s_waitcnt lgkmcnt(0)" ::: "memory"); \
    __builtin_amdgcn_s_barrier(); \
  } while (0)

// XOR swizzle on bits 4-6 using row bits 1-3 (0 measured conflicts, rounds 2-4).
__device__ __forceinline__ int swz(int row, int kbyte) {
  return (row * 64 + kbyte) ^ (((row >> 1) & 7) << 4);
}

// ---- prep: Wtile[T][c][idx] = 16B bf16 chunk for (o = c*256 + idx>>2,
//      k = T*32 + (idx&3)*8), k<768 -> We else Ww. Thread-linear per tile. ----
__global__ void prep_w(const float* __restrict__ We, const float* __restrict__ Ww,
                       unsigned short* __restrict__ Wtile) {
  int i = blockIdx.x * blockDim.x + threadIdx.x;  // 147456 threads, 8 bf16 each
  int base = i * 8;
  int o = base / KTOT;
  int k = base - o * KTOT;
  const float* src = (k < DD) ? (We + (size_t)o * DD + k)
                              : (Ww + (size_t)o * DD + (k - DD));
  f32x4 v0 = *(const f32x4*)src;
  f32x4 v1 = *(const f32x4*)(src + 4);
  union { bf16 h[8]; u32x4 q; } u;
  u.h[0]=(bf16)v0[0]; u.h[1]=(bf16)v0[1]; u.h[2]=(bf16)v0[2]; u.h[3]=(bf16)v0[3];
  u.h[4]=(bf16)v1[0]; u.h[5]=(bf16)v1[1]; u.h[6]=(bf16)v1[2]; u.h[7]=(bf16)v1[3];
  int T = k >> 5, c = o >> 8;
  int idx = ((o & 255) << 2) | ((k & 31) >> 3);
  *(u32x4*)(Wtile + (size_t)T * 24576 + c * 8192 + idx * 8) = u.q;
}

__global__ __launch_bounds__(1024, 4)
void msg_kernel(const float* __restrict__ h_w, const float* __restrict__ e_vw,
                const unsigned short* __restrict__ Wtile,
                const float* __restrict__ be, const float* __restrict__ bw,
                float* __restrict__ out) {
  // A: [0, 2*49152) dbuf ; B: [98304, +2*4096) dbuf ; bias: [106496, +3072)
  __shared__ __align__(16) unsigned char smem[2 * 49152 + 2 * 4096 + BM * 4];
  float* bias_s = (float*)(smem + 106496);

  const int tid = threadIdx.x;
  const int bb  = blockIdx.x >> 2;          // batch
  const int bn0 = (blockIdx.x & 3) * BN;    // n-slice

  if (tid < BM) bias_s[tid] = be[tid] + bw[tid];

  // ---- A staging map: chunk c -> row c*256 + (tid>>2), kbytes (tid&3)*16 ----
  const unsigned short* pA = Wtile + (size_t)tid * 8;
  const int wAr = tid >> 2, wAk = (tid & 3) * 16;

  // ---- B staging map: n = tid&63, k-group = wave id (2 k per thread) ----
  const int nB = tid & 63, kg = tid >> 6;
  const size_t bofs = (size_t)bb * DD * NCOL + (size_t)(kg * 2) * NCOL + bn0 + nB;
  const float* pE = e_vw + bofs;
  const float* pH = h_w  + bofs;
  const int wB = swz(nB, kg * 4);

  u32x4 aR[3];                 // A prefetch regs (bf16 bits)
  float bE0, bE1, bO0, bO1;    // B prefetch regs, even/odd tile sets

  auto issueA = [&](int T) {
    const unsigned short* p = pA + (size_t)T * 24576;
    aR[0] = *(const u32x4*)(p);
    aR[1] = *(const u32x4*)(p + 8192);
    aR[2] = *(const u32x4*)(p + 16384);
  };
  auto storeA = [&](int buf) {
    unsigned char* base = smem + buf * 49152;
    #pragma unroll
    for (int c = 0; c < 3; ++c)
      *(u32x4*)(base + swz(c * 256 + wAr, wAk)) = aR[c];
  };
  auto issueB = [&](int T, float& r0, float& r1) {
    int TT = T > 47 ? 47 : T;
    const float* p = (TT < 24) ? (pE + (size_t)TT * BK * NCOL)
                               : (pH + (size_t)(TT - 24) * BK * NCOL);
    r0 = p[0];
    r1 = p[NCOL];
  };
  auto storeB = [&](int buf, float r0, float r1) {
    unsigned char* base = smem + 98304 + buf * 4096;
    union { bf16 h[2]; unsigned int q; } u;
    u.h[0] = (bf16)r0; u.h[1] = (bf16)r1;
    *(unsigned int*)(base + wB) = u.q;
  };

  // ---- compute map: 16 waves = 8m x 2n, wave tile 96x64 ----
  const int lane = tid & 63, wid = tid >> 6;
  const int wm = wid >> 1, wn = wid & 1;
  const int lr = lane & 15, kch = (lane >> 4) * 16;
  f32x4 acc[6][2] = {};

  auto compute = [&](int buf) {
    const unsigned char* baseA = smem + buf * 49152;
    const unsigned char* baseB = smem + 98304 + buf * 4096;
    bf16x8 af[6], bfr[2];
    #pragma unroll
    for (int m = 0; m < 6; ++m)
      af[m] = *(const bf16x8*)(baseA + swz(wm * 96 + m * 16 + lr, kch));
    #pragma unroll
    for (int n = 0; n < 2; ++n)
      bfr[n] = *(const bf16x8*)(baseB + swz(wn * 32 + n * 16 + lr, kch));
    #pragma unroll
    for (int m = 0; m < 6; ++m)
      #pragma unroll
      for (int n = 0; n < 2; ++n)
        acc[m][n] = __builtin_amdgcn_mfma_f32_16x16x32_bf16(af[m], bfr[n], acc[m][n], 0, 0, 0);
  };

  // ---- prologue: stage tile 0; leave tiles 1 (A,B) and 2 (B) in flight ----
  issueB(0, bE0, bE1);
  issueA(0);
  storeA(0);
  storeB(0, bE0, bE1);
  issueB(1, bO0, bO1);
  issueA(1);
  issueB(2, bE0, bE1);
  BAR();

  // ---- main loop: step S computes tile S, stores S+1, issues A:S+2 B:S+3 ----
  for (int it = 0; it < 46; it += 2) {
    // even step: compute buf0
    compute(0);
    storeA(1);                 // tile it+1 (waits aR, issued last step)
    storeB(1, bO0, bO1);       // tile it+1
    issueA(it + 2);
    issueB(it + 3, bO0, bO1);
    BAR();

    // odd step: compute buf1
    compute(1);
    storeA(0);                 // tile it+2
    storeB(0, bE0, bE1);       // tile it+2
    issueA(it + 3);
    issueB(it + 4, bE0, bE1);
    BAR();
  }
  // tail: tiles 46 (buf0), 47 (regs -> buf1)
  compute(0);
  storeA(1);                   // tile 47
  storeB(1, bO0, bO1);         // tile 47
  BAR();
  compute(1);

  // ---- epilogue: bias + store. C/D: col=lane&15, row=(lane>>4)*4+reg ----
  float* po = out + (size_t)bb * DD * NCOL;
  const int g4 = (lane >> 4) * 4;
  #pragma unroll
  for (int m = 0; m < 6; ++m) {
    const int r0 = wm * 96 + m * 16 + g4;
    #pragma unroll
    for (int n = 0; n < 2; ++n) {
      const int col = bn0 + wn * 32 + n * 16 + lr;
      #pragma unroll
      for (int j = 0; j < 4; ++j)
        po[(size_t)(r0 + j) * NCOL + col] = acc[m][n][j] + bias_s[r0 + j];
    }
  }
}

extern "C" void kernel_launch(void* const* d_in, const int* in_sizes, int n_in,
                              void* d_out, int out_size, void* d_ws, size_t ws_size,
                              hipStream_t stream) {
  // inputs: 0:h_v(unused) 1:h_w 2:e_vw 3:We 4:be 5:Ww 6:bw
  const float* h_w  = (const float*)d_in[1];
  const float* e_vw = (const float*)d_in[2];
  const float* We   = (const float*)d_in[3];
  const float* be   = (const float*)d_in[4];
  const float* Ww   = (const float*)d_in[5];
  const float* bw   = (const float*)d_in[6];
  float* out = (float*)d_out;
  unsigned short* Wtile = (unsigned short*)d_ws;  // 48 tiles * 48KB = 2.36 MB

  prep_w<<<dim3(576), 256, 0, stream>>>(We, Ww, Wtile);
  msg_kernel<<<dim3(512), 1024, 0, stream>>>(h_w, e_vw, Wtile, be, bw, out);
}